// Round 7
// baseline (795.223 us; speedup 1.0000x reference)
//
#include <hip/hip_runtime.h>
#include <math.h>

#define NPIX  4096
#define NC    2049          // NPIX/2 + 1
#define NVIS  500000
#define NTAPS 36
#define FFT_N 4096
#define FFT_T 256

// native clang vector types (required by __builtin_nontemporal_load)
typedef int   vi4 __attribute__((ext_vector_type(4)));
typedef float vf4 __attribute__((ext_vector_type(4)));

// 16-point DFT constants
#define C16_1 0.923879532511286756f   // cos(pi/8)
#define S16_1 0.382683432365089772f   // sin(pi/8)
#define RSQ2  0.707106781186547524f   // sqrt(2)/2

#define CMUL(ar,ai,br,bi) { float _tr = (ar)*(br) - (ai)*(bi); \
                            (ai) = (ar)*(bi) + (ai)*(br); (ar) = _tr; }
#define MULNEGI(ar,ai)    { float _t = (ar); (ar) = (ai); (ai) = -_t; }

// forward 4-pt DFT (W4 = -i), in place on 4 complex regs
#define DFT4(r0,i0,r1,i1,r2,i2,r3,i3) { \
  float tr02=(r0)+(r2), ti02=(i0)+(i2), dr02=(r0)-(r2), di02=(i0)-(i2); \
  float tr13=(r1)+(r3), ti13=(i1)+(i3), dr13=(r1)-(r3), di13=(i1)-(i3); \
  (r0)=tr02+tr13; (i0)=ti02+ti13; \
  (r1)=dr02+di13; (i1)=di02-dr13; \
  (r2)=tr02-tr13; (i2)=ti02-ti13; \
  (r3)=dr02-di13; (i3)=di02+dr13; }

// ---------------------------------------------------------------------------
// Twiddles: tw[k] = exp(-2*pi*i*k/4096), k = 0..4095
// ---------------------------------------------------------------------------
__global__ void init_twiddles(float2* tw) {
    int k = blockIdx.x * blockDim.x + threadIdx.x;
    if (k < FFT_N) {
        double ang = -2.0 * M_PI * (double)k / (double)FFT_N;
        tw[k] = make_float2((float)cos(ang), (float)sin(ang));
    }
}

// ---------------------------------------------------------------------------
// In-register 16-pt DFT (4x4 Cooley-Tukey). All indices compile-time.
// Input x[n] in regs [n]. Output X[k] lands in reg p = 4*(k&3) + (k>>2).
// ---------------------------------------------------------------------------
__device__ __forceinline__ void dft16(float xr[16], float xi[16]) {
    #pragma unroll
    for (int m2 = 0; m2 < 4; ++m2)
        DFT4(xr[m2],    xi[m2],    xr[4+m2],  xi[4+m2],
             xr[8+m2],  xi[8+m2],  xr[12+m2], xi[12+m2]);
    CMUL(xr[5],  xi[5],   C16_1, -S16_1);   // W^1
    CMUL(xr[6],  xi[6],   RSQ2,  -RSQ2);    // W^2
    CMUL(xr[7],  xi[7],   S16_1, -C16_1);   // W^3
    CMUL(xr[9],  xi[9],   RSQ2,  -RSQ2);    // W^2
    MULNEGI(xr[10], xi[10]);                // W^4 = -i
    CMUL(xr[11], xi[11], -RSQ2,  -RSQ2);    // W^6
    CMUL(xr[13], xi[13],  S16_1, -C16_1);   // W^3
    CMUL(xr[14], xi[14], -RSQ2,  -RSQ2);    // W^6
    CMUL(xr[15], xi[15], -C16_1,  S16_1);   // W^9 = -W^1
    #pragma unroll
    for (int q1 = 0; q1 < 4; ++q1)
        DFT4(xr[4*q1],   xi[4*q1],   xr[4*q1+1], xi[4*q1+1],
             xr[4*q1+2], xi[4*q1+2], xr[4*q1+3], xi[4*q1+3]);
}

// ---------------------------------------------------------------------------
// 4096-pt complex FFT: 3 phases of radix-16, 16 points/thread, 256 threads.
// ---------------------------------------------------------------------------
__device__ __forceinline__ void fft4096_reg(float2* z, float2* dst,
                                            const float2* __restrict__ tw,
                                            int t) {
    float xr[16], xi[16];

    // ---- phase 1: t = 16*n2 + n3; DFT over n1 (stride 256). Conflict-free.
    #pragma unroll
    for (int n1 = 0; n1 < 16; ++n1) {
        float2 v = z[t + 256 * n1]; xr[n1] = v.x; xi[n1] = v.y;
    }
    dft16(xr, xi);
    {
        int n2 = t >> 4;
        #pragma unroll
        for (int k1 = 1; k1 < 16; ++k1) {
            int p = ((k1 & 3) << 2) | (k1 >> 2);
            float2 w = tw[(16 * n2 * k1) & 4095];
            CMUL(xr[p], xi[p], w.x, w.y);
        }
    }
    #pragma unroll
    for (int k1 = 0; k1 < 16; ++k1) {
        int p = ((k1 & 3) << 2) | (k1 >> 2);
        z[t + 256 * k1] = make_float2(xr[p], xi[p]);
    }
    __syncthreads();

    // ---- phase 2: k1 = t>>4, n3 = t&15; DFT over n2 (stride 16). 4-way banked.
    {
        int k1 = t >> 4, n3 = t & 15;
        #pragma unroll
        for (int m = 0; m < 16; ++m) {
            float2 v = z[256 * k1 + 16 * m + n3]; xr[m] = v.x; xi[m] = v.y;
        }
        __syncthreads();                   // all reads done before relayout writes
        dft16(xr, xi);
        #pragma unroll
        for (int k2 = 0; k2 < 16; ++k2) {
            int p = ((k2 & 3) << 2) | (k2 >> 2);
            float2 w = tw[(n3 * (k1 + 16 * k2)) & 4095];
            CMUL(xr[p], xi[p], w.x, w.y);
            z[k1 + 16 * k2 + 256 * n3] = make_float2(xr[p], xi[p]);
        }
    }
    __syncthreads();

    // ---- phase 3: t = k1 + 16*k2; DFT over n3 (stride 256). Conflict-free.
    #pragma unroll
    for (int m = 0; m < 16; ++m) {
        float2 v = z[t + 256 * m]; xr[m] = v.x; xi[m] = v.y;
    }
    dft16(xr, xi);
    #pragma unroll
    for (int k3 = 0; k3 < 16; ++k3) {
        int p = ((k3 & 3) << 2) | (k3 >> 2);
        dst[t + 256 * k3] = make_float2(xr[p], xi[p]);   // X[t + 256*k3]
    }
}

// ---------------------------------------------------------------------------
// Pass A: rows 2b, 2b+1 packed as re/im of ONE complex FFT; unpack to
// rfft rows 2b and 2b+1 of A[4096][2049] (float2 interleaved).
// ---------------------------------------------------------------------------
__global__ __launch_bounds__(FFT_T) void rowpair_fft(const float* __restrict__ img,
                                                     const float* __restrict__ cf,
                                                     const float2* __restrict__ tw,
                                                     float2* __restrict__ aout,
                                                     float scale) {
    __shared__ float2 z[FFT_N];            // 32 KB
    int t  = threadIdx.x;
    int r0 = 2 * blockIdx.x;

    const float4* i0 = (const float4*)(img + (size_t)r0 * NPIX);
    const float4* c0 = (const float4*)(cf  + (size_t)r0 * NPIX);
    const float4* i1 = (const float4*)(img + (size_t)(r0 + 1) * NPIX);
    const float4* c1 = (const float4*)(cf  + (size_t)(r0 + 1) * NPIX);
    #pragma unroll
    for (int j = 0; j < 4; ++j) {
        int s = t + 256 * j;               // float4 slot
        float4 a0 = i0[s], b0 = c0[s], a1 = i1[s], b1 = c1[s];
        z[4*s+0] = make_float2(a0.x * b0.x * scale, a1.x * b1.x * scale);
        z[4*s+1] = make_float2(a0.y * b0.y * scale, a1.y * b1.y * scale);
        z[4*s+2] = make_float2(a0.z * b0.z * scale, a1.z * b1.z * scale);
        z[4*s+3] = make_float2(a0.w * b0.w * scale, a1.w * b1.w * scale);
    }
    __syncthreads();

    fft4096_reg(z, z, tw, t);
    __syncthreads();

    // unpack: Xeven(k) = (Z(k)+conj(Z(-k)))/2 ; Xodd(k) = -i/2 (Z(k)-conj(Z(-k)))
    size_t ro0 = (size_t)r0 * NC, ro1 = ro0 + NC;
    #pragma unroll
    for (int j = 0; j < 9; ++j) {
        int k = t + 256 * j;
        if (k <= 2048) {
            float2 zk = z[k];
            float2 zm = z[(FFT_N - k) & (FFT_N - 1)];
            aout[ro0 + k] = make_float2(0.5f * (zk.x + zm.x), 0.5f * (zk.y - zm.y));
            aout[ro1 + k] = make_float2(0.5f * (zk.y + zm.y), 0.5f * (zm.x - zk.x));
        }
    }
}

// ---------------------------------------------------------------------------
// Pass B: float2 transpose [4096][2049] -> [2049][4096]
// ---------------------------------------------------------------------------
#define TDIM 32
__global__ __launch_bounds__(256) void transpose2(const float2* __restrict__ in,
                                                  float2* __restrict__ out) {
    __shared__ float2 tile[TDIM][TDIM + 1];
    const int H = NPIX, W = NC;
    int bx = blockIdx.x * TDIM;            // along W (2049)
    int by = blockIdx.y * TDIM;            // along H (4096)
    int tx = threadIdx.x;                  // 0..31
    int ty = threadIdx.y;                  // 0..7

    #pragma unroll
    for (int i = ty; i < TDIM; i += 8) {
        int x = bx + tx, y = by + i;
        if (x < W) tile[i][tx] = in[(size_t)y * W + x];
    }
    __syncthreads();
    #pragma unroll
    for (int i = ty; i < TDIM; i += 8) {
        int oy = bx + i;                   // along W
        int ox = by + tx;                  // along H
        if (oy < W) out[(size_t)oy * H + ox] = tile[tx][i];
    }
}

// ---------------------------------------------------------------------------
// Pass C: complex 4096-pt FFT per transposed row (= image column); writes the
// final interleaved grid[c][r] directly from phase 3 (coalesced).
// ---------------------------------------------------------------------------
__global__ __launch_bounds__(FFT_T) void col_fft(const float2* __restrict__ tin,
                                                 const float2* __restrict__ tw,
                                                 float2* __restrict__ grid) {
    __shared__ float2 z[FFT_N];
    int t = threadIdx.x;
    size_t off = (size_t)blockIdx.x * FFT_N;

    const float4* s4 = (const float4*)(tin + off);   // 2 complex per float4
    #pragma unroll
    for (int j = 0; j < 8; ++j) {
        int s = t + 256 * j;
        float4 v = s4[s];
        z[2*s]   = make_float2(v.x, v.y);
        z[2*s+1] = make_float2(v.z, v.w);
    }
    __syncthreads();

    fft4096_reg(z, grid + off, tw, t);
}

// ---------------------------------------------------------------------------
// Pass D: 36-tap gather, MLP-restructured.
//   1) load all 36 indices (native-vector int4, non-temporal)
//   2) convert all to transposed offsets (col*4096 + row)
//   3) issue ALL 36 float2 gathers back-to-back (max outstanding loads)
//   4) stream weights (non-temporal) and accumulate
// ---------------------------------------------------------------------------
__global__ __launch_bounds__(256) void gather_k(const float* __restrict__ Cre,
                                                const float* __restrict__ Cim,
                                                const int* __restrict__ cols,
                                                const float2* __restrict__ grid,
                                                float* __restrict__ out) {
    int v = blockIdx.x * blockDim.x + threadIdx.x;
    if (v >= NVIS) return;

    const vi4* c4 = (const vi4*)cols + (size_t)v * 9;
    int off[NTAPS];
    #pragma unroll
    for (int u = 0; u < 9; ++u) {
        vi4 id = __builtin_nontemporal_load(&c4[u]);
        off[4*u+0] = id.x; off[4*u+1] = id.y;
        off[4*u+2] = id.z; off[4*u+3] = id.w;
    }
    #pragma unroll
    for (int j = 0; j < NTAPS; ++j) {
        int row = off[j] / NC;             // magic-mul division
        off[j]  = (off[j] - row * NC) * FFT_N + row;
    }

    float2 g[NTAPS];
    #pragma unroll
    for (int j = 0; j < NTAPS; ++j) g[j] = grid[off[j]];

    const vf4* r4 = (const vf4*)Cre + (size_t)v * 9;
    const vf4* m4 = (const vf4*)Cim + (size_t)v * 9;
    float ar = 0.f, ai = 0.f;
    #pragma unroll
    for (int u = 0; u < 9; ++u) {
        vf4 wr = __builtin_nontemporal_load(&r4[u]);
        vf4 wi = __builtin_nontemporal_load(&m4[u]);
        ar = fmaf(wr.x, g[4*u+0].x, ar); ai = fmaf(wi.x, g[4*u+0].y, ai);
        ar = fmaf(wr.y, g[4*u+1].x, ar); ai = fmaf(wi.y, g[4*u+1].y, ai);
        ar = fmaf(wr.z, g[4*u+2].x, ar); ai = fmaf(wi.z, g[4*u+2].y, ai);
        ar = fmaf(wr.w, g[4*u+3].x, ar); ai = fmaf(wi.w, g[4*u+3].y, ai);
    }
    out[v]        = ar;
    out[NVIS + v] = ai;
}

// ---------------------------------------------------------------------------
extern "C" void kernel_launch(void* const* d_in, const int* in_sizes, int n_in,
                              void* d_out, int out_size, void* d_ws, size_t ws_size,
                              hipStream_t stream) {
    const float* image   = (const float*)d_in[0];
    const float* corrfun = (const float*)d_in[1];
    const float* Cre     = (const float*)d_in[2];
    const float* Cim     = (const float*)d_in[3];
    const int*   cols    = (const int*)d_in[4];
    float*       out     = (float*)d_out;

    char*  ws     = (char*)d_ws;
    size_t plane2 = (size_t)NPIX * NC * sizeof(float2);   // 67,141,632 B
    float2* A    = (float2*)(ws + 0);           // pass A out; reused as final grid
    float2* T    = (float2*)(ws + plane2);      // transposed [2049][4096]
    float2* tw   = (float2*)(ws + 2 * plane2);  // 32 KB twiddles

    double dll   = 0.005 * (M_PI / (180.0 * 3600.0));
    float  scale = (float)(dll * dll);

    init_twiddles<<<FFT_N / 256, 256, 0, stream>>>(tw);

    // A: 2048 packed real-pair row FFTs -> A[4096][2049] float2
    rowpair_fft<<<NPIX / 2, FFT_T, 0, stream>>>(image, corrfun, tw, A, scale);

    // B: transpose -> T[2049][4096]
    dim3 tb(TDIM, 8);
    dim3 tg((NC + TDIM - 1) / TDIM, NPIX / TDIM);
    transpose2<<<tg, tb, 0, stream>>>(A, T);

    // C: 2049 column FFTs; final grid written into A (interleaved, transposed)
    col_fft<<<NC, FFT_T, 0, stream>>>(T, tw, A);

    // D: sparse 36-tap gather (MLP-restructured)
    gather_k<<<(NVIS + 255) / 256, 256, 0, stream>>>(Cre, Cim, cols, A, out);
}